// Round 12
// baseline (1152.327 us; speedup 1.0000x reference)
//
#include <hip/hip_runtime.h>
#include <hip/hip_bf16.h>
#include <math.h>

#define D_MODEL 1024
#define NHEAD   16
#define DKH     64
#define BATCH   4
#define SEQ     2048
#define BH      (BATCH*NHEAD)    // 64
#define MROWS   (BATCH*SEQ)      // 8192

typedef __attribute__((ext_vector_type(8))) short bf16x8;
typedef __attribute__((ext_vector_type(4))) short bf16x4;
typedef __attribute__((ext_vector_type(4))) float f32x4;

__device__ __forceinline__ short f2bf(float x){
    union { float f; unsigned u; } v; v.f = x;
    unsigned r = (v.u + 0x7fffu + ((v.u >> 16) & 1u)) >> 16;
    return (short)r;
}
__device__ __forceinline__ float bf2f(short s){
    union { unsigned u; float f; } v; v.u = ((unsigned)(unsigned short)s) << 16; return v.f;
}
__device__ __forceinline__ unsigned fasu(float x){ union{float f;unsigned u;} v; v.f=x; return v.u; }
__device__ __forceinline__ float uasf(unsigned x){ union{unsigned u;float f;} v; v.u=x; return v.f; }
__device__ __forceinline__ f32x4 mfma16(bf16x8 a, bf16x8 b, f32x4 c){
    return __builtin_amdgcn_mfma_f32_16x16x32_bf16(a, b, c, 0, 0, 0);
}

// Dekker-style truncation split of 4 fp32 into packed bf16 hi (uint2) + lo (uint2).
__device__ __forceinline__ void split4(float4 f, uint2* hi, uint2* lo){
    unsigned u0=fasu(f.x), u1=fasu(f.y), u2=fasu(f.z), u3=fasu(f.w);
    unsigned h0=u0&0xFFFF0000u, h1=u1&0xFFFF0000u, h2=u2&0xFFFF0000u, h3=u3&0xFFFF0000u;
    float l0=f.x-uasf(h0), l1=f.y-uasf(h1), l2=f.z-uasf(h2), l3=f.w-uasf(h3);
    hi->x = h1 | (u0>>16);
    hi->y = h3 | (u2>>16);
    unsigned v0=fasu(l0), v1=fasu(l1), v2=fasu(l2), v3=fasu(l3);
    lo->x = (v1&0xFFFF0000u) | (v0>>16);
    lo->y = (v3&0xFFFF0000u) | (v2>>16);
}

// ---------------------------------------------------------------------------
// Kernel A: QKV projection via bf16-split MFMA + fused RoPE epilogue.
// BK=32 (LDS 32KB) + __launch_bounds__(256,4): 4 blocks/CU (was 2 at BK=64) —
// round-7 PMC showed both pipes <20% at Occupancy 24% => latency-bound.
// ---------------------------------------------------------------------------
__global__ __launch_bounds__(256, 4)
void gemm_qkv_kernel(const float* __restrict__ x,
                     const int*   __restrict__ pos,
                     const float* __restrict__ Wq,
                     const float* __restrict__ Wk,
                     const float* __restrict__ Wv,
                     float* __restrict__ qb,
                     float* __restrict__ kb,
                     float* __restrict__ vb)
{
    const int which = blockIdx.z;
    const float* __restrict__ W    = (which==0)?Wq:(which==1)?Wk:Wv;
    float*       __restrict__ outb = (which==0)?qb:(which==1)?kb:vb;

    __shared__ short lAh[128*32], lAl[128*32], lBh[128*32], lBl[128*32];

    const int t  = threadIdx.x;
    const int w  = t >> 6, l = t & 63;
    const int ln = l & 15, g = l >> 4;
    const int wr = w >> 1, wc = w & 1;
    const int m0 = blockIdx.x * 128, n0 = blockIdx.y * 128;

    f32x4 acc[4][4];
    #pragma unroll
    for (int mi=0;mi<4;mi++)
        #pragma unroll
        for (int ni=0;ni<4;ni++) acc[mi][ni] = (f32x4){0.f,0.f,0.f,0.f};

    for (int k0 = 0; k0 < D_MODEL; k0 += 32){
        __syncthreads();
        #pragma unroll
        for (int i=0;i<4;i++){
            int c    = i*256 + t;          // float4 unit, 0..1023
            int row  = c >> 3;             // 0..127
            int col4 = (c & 7) << 2;
            int si   = (row*32 + col4) ^ ((row & 7) << 3);
            float4 fa = *(const float4*)&x[(size_t)(m0+row)*D_MODEL + k0 + col4];
            uint2 ah_, al_;
            split4(fa, &ah_, &al_);
            *(uint2*)&lAh[si] = ah_;
            *(uint2*)&lAl[si] = al_;
            float4 fb = *(const float4*)&W[(size_t)(n0+row)*D_MODEL + k0 + col4];
            uint2 bh_, bl_;
            split4(fb, &bh_, &bl_);
            *(uint2*)&lBh[si] = bh_;
            *(uint2*)&lBl[si] = bl_;
        }
        __syncthreads();

        bf16x8 ah[4], al[4], bh[4], bl[4];
        #pragma unroll
        for (int mi=0;mi<4;mi++){
            int row = wr*64 + mi*16 + ln;
            int si  = (row*32 + g*8) ^ ((row & 7) << 3);
            ah[mi] = *(const bf16x8*)&lAh[si];
            al[mi] = *(const bf16x8*)&lAl[si];
        }
        #pragma unroll
        for (int ni=0;ni<4;ni++){
            int row = wc*64 + ni*16 + ln;
            int si  = (row*32 + g*8) ^ ((row & 7) << 3);
            bh[ni] = *(const bf16x8*)&lBh[si];
            bl[ni] = *(const bf16x8*)&lBl[si];
        }
        #pragma unroll
        for (int mi=0;mi<4;mi++)
            #pragma unroll
            for (int ni=0;ni<4;ni++){
                acc[mi][ni] = mfma16(ah[mi], bh[ni], acc[mi][ni]);
                acc[mi][ni] = mfma16(ah[mi], bl[ni], acc[mi][ni]);
                acc[mi][ni] = mfma16(al[mi], bh[ni], acc[mi][ni]);
            }
    }

    // Epilogue: RoPE (q,k only) + fp32 head-major store.
    #pragma unroll
    for (int mi=0;mi<4;mi++){
        #pragma unroll
        for (int ni=0;ni<4;ni++){
            const int n  = n0 + wc*64 + ni*16 + ln;
            const int h  = n >> 6;
            const int cc = n & 63;
            float invf = 0.f;
            if (which < 2){
                const int j = cc >> 1;
                invf = __expf(-(float)j * 0.2878231366242557f);  // ln(1e4)/32
            }
            #pragma unroll
            for (int r=0;r<4;r++){
                const int m = m0 + wr*64 + mi*16 + g*4 + r;
                const int b = m >> 11;
                const int s = m & 2047;
                float v = acc[mi][ni][r];
                float p = __shfl_xor(v, 1);   // partner column n^1 (same row)
                float res;
                if (which < 2){
                    float ang = (float)pos[s] * invf;
                    float sn, cs; __sincosf(ang, &sn, &cs);
                    res = ((n & 1) == 0) ? (v*cs - p*sn) : (p*sn + v*cs);
                } else {
                    res = v;
                }
                outb[(((size_t)(b*NHEAD + h))*SEQ + s)*DKH + cc] = res;
            }
        }
    }
}

// ---------------------------------------------------------------------------
// Kernel B: causal flash attention via bf16-split MFMA.
// CHANGE vs measured round-7 code: per-wave P buffer halved (32x32, two-half
// pack+PV) => LDS 64KB -> 48KB => 3 blocks/CU (was 2). Numerics identical
// (same values, same accumulation order; P buffer is per-wave, no barrier
// semantics involved — same write-then-read pattern as measured rounds 2/7).
// ---------------------------------------------------------------------------
__global__ __launch_bounds__(256, 3)
void flash_mfma_kernel(const float* __restrict__ qb,
                       const float* __restrict__ kb,
                       const float* __restrict__ vb,
                       float* __restrict__ ob)
{
    const int qt = (int)(gridDim.x - 1) - (int)blockIdx.x;   // big tiles first
    const int bh = blockIdx.y;
    const int t  = threadIdx.x;
    const int w  = t >> 6;
    const int l  = t & 63;
    const int ln = l & 15;
    const int g  = l >> 4;

    __shared__ short lKhi[4096], lKlo[4096];       // [c=64][k=64]  16KB
    __shared__ short lVhi[4096], lVlo[4096];       // [d=64][c=64]  16KB
    __shared__ short lPhi[4][1024], lPlo[4][1024]; // per-wave [r=32][c=32] 16KB

    const int swz = (ln & 7) << 3;

    // Q frags (hi/lo, scaled by 1/8)
    bf16x8 qh[2][2], ql[2][2];
    {
        const int qrow0 = qt*128 + w*32;
        #pragma unroll
        for (int rt=0; rt<2; rt++){
            #pragma unroll
            for (int ks=0; ks<2; ks++){
                const float* qp = qb + ((size_t)bh*SEQ + qrow0 + rt*16 + ln)*DKH + ks*32 + g*8;
                float4 x0 = *(const float4*)qp;
                float4 x1 = *(const float4*)(qp+4);
                float xs[8] = {x0.x,x0.y,x0.z,x0.w,x1.x,x1.y,x1.z,x1.w};
                short hi[8], lo[8];
                #pragma unroll
                for (int i=0;i<8;i++){
                    float v = xs[i]*0.125f;
                    hi[i] = f2bf(v);
                    lo[i] = f2bf(v - bf2f(hi[i]));
                }
                qh[rt][ks] = (bf16x8){hi[0],hi[1],hi[2],hi[3],hi[4],hi[5],hi[6],hi[7]};
                ql[rt][ks] = (bf16x8){lo[0],lo[1],lo[2],lo[3],lo[4],lo[5],lo[6],lo[7]};
            }
        }
    }

    f32x4 oacc[2][4];
    #pragma unroll
    for (int rt=0; rt<2; rt++)
        #pragma unroll
        for (int dm=0; dm<4; dm++)
            oacc[rt][dm] = (f32x4){0.f,0.f,0.f,0.f};
    float m_run[2] = {-3.0e38f, -3.0e38f};
    float l_run[2] = {0.f, 0.f};

    const int ktmax = 2*qt + 1;
    for (int kt = 0; kt <= ktmax; ++kt){
        __syncthreads();

        // ---- stage K tile (hi/lo) ----
        #pragma unroll
        for (int rep=0; rep<4; rep++){
            int idx = t + rep*256;
            int row = idx >> 4;
            int kc  = (idx & 15) << 2;
            float4 kx = *(const float4*)&kb[((size_t)bh*SEQ + kt*64 + row)*DKH + kc];
            float xs[4] = {kx.x,kx.y,kx.z,kx.w};
            short hi[4], lo[4];
            #pragma unroll
            for (int i=0;i<4;i++){
                hi[i] = f2bf(xs[i]);
                lo[i] = f2bf(xs[i] - bf2f(hi[i]));
            }
            int si = (row*64 + kc) ^ ((row&7)<<3);
            *(bf16x4*)&lKhi[si] = (bf16x4){hi[0],hi[1],hi[2],hi[3]};
            *(bf16x4*)&lKlo[si] = (bf16x4){lo[0],lo[1],lo[2],lo[3]};
        }
        // ---- stage V^T tile (hi/lo) ----
        {
            int d  = t & 63;
            int c0 = (t >> 6) << 4;
            const float* vcol = vb + ((size_t)bh*SEQ + kt*64 + c0)*DKH + d;
            float vvf[16];
            #pragma unroll
            for (int j=0;j<16;j++) vvf[j] = vcol[(size_t)j*DKH];
            short hh[16], ll[16];
            #pragma unroll
            for (int j=0;j<16;j++){
                hh[j] = f2bf(vvf[j]);
                ll[j] = f2bf(vvf[j] - bf2f(hh[j]));
            }
            int si0 = (d*64 + c0)     ^ ((d&7)<<3);
            int si1 = (d*64 + c0 + 8) ^ ((d&7)<<3);
            *(bf16x8*)&lVhi[si0] = (bf16x8){hh[0],hh[1],hh[2],hh[3],hh[4],hh[5],hh[6],hh[7]};
            *(bf16x8*)&lVhi[si1] = (bf16x8){hh[8],hh[9],hh[10],hh[11],hh[12],hh[13],hh[14],hh[15]};
            *(bf16x8*)&lVlo[si0] = (bf16x8){ll[0],ll[1],ll[2],ll[3],ll[4],ll[5],ll[6],ll[7]};
            *(bf16x8*)&lVlo[si1] = (bf16x8){ll[8],ll[9],ll[10],ll[11],ll[12],ll[13],ll[14],ll[15]};
        }
        __syncthreads();

        if (kt*64 > qt*128 + w*32 + 31) continue;   // wave fully masked

        // ---- QK^T (swapped): s[cm][rn] = S^T ----
        f32x4 s[4][2];
        #pragma unroll
        for (int cm=0; cm<4; cm++)
            #pragma unroll
            for (int rn=0; rn<2; rn++)
                s[cm][rn] = (f32x4){0.f,0.f,0.f,0.f};

        #pragma unroll
        for (int ks=0; ks<2; ks++){
            #pragma unroll
            for (int cm=0; cm<4; cm++){
                int si = ((cm*16 + ln)*64 + ks*32 + g*8) ^ swz;
                bf16x8 ah = *(const bf16x8*)&lKhi[si];
                bf16x8 al = *(const bf16x8*)&lKlo[si];
                #pragma unroll
                for (int rn=0; rn<2; rn++){
                    s[cm][rn] = mfma16(ah, qh[rn][ks], s[cm][rn]);
                    s[cm][rn] = mfma16(ah, ql[rn][ks], s[cm][rn]);
                    s[cm][rn] = mfma16(al, qh[rn][ks], s[cm][rn]);
                }
            }
        }

        // ---- causal mask ----
        if (kt*64 + 63 > qt*128 + w*32){
            #pragma unroll
            for (int cm=0; cm<4; cm++){
                #pragma unroll
                for (int rn=0; rn<2; rn++){
                    #pragma unroll
                    for (int r=0; r<4; r++){
                        int cg = kt*64 + cm*16 + g*4 + r;
                        int rg = qt*128 + w*32 + rn*16 + ln;
                        if (cg > rg) s[cm][rn][r] = -3.0e38f;
                    }
                }
            }
        }

        // ---- online softmax ----
        float alpha[2];
        #pragma unroll
        for (int rn=0; rn<2; rn++){
            float mx = -3.0e38f;
            #pragma unroll
            for (int cm=0; cm<4; cm++)
                #pragma unroll
                for (int r=0; r<4; r++) mx = fmaxf(mx, s[cm][rn][r]);
            mx = fmaxf(mx, __shfl_xor(mx, 16));
            mx = fmaxf(mx, __shfl_xor(mx, 32));
            float mnew = fmaxf(m_run[rn], mx);
            alpha[rn] = __expf(m_run[rn] - mnew);
            m_run[rn] = mnew;
            float ls = 0.f;
            #pragma unroll
            for (int cm=0; cm<4; cm++){
                #pragma unroll
                for (int r=0; r<4; r++){
                    float p = __expf(s[cm][rn][r] - mnew);
                    s[cm][rn][r] = p;
                    ls += p;
                }
            }
            ls += __shfl_xor(ls, 16);
            ls += __shfl_xor(ls, 32);
            l_run[rn] = l_run[rn]*alpha[rn] + ls;
        }

        // ---- rescale O ----
        #pragma unroll
        for (int rt=0; rt<2; rt++){
            #pragma unroll
            for (int r=0; r<4; r++){
                float a = __shfl(alpha[rt], g*4 + r);
                #pragma unroll
                for (int dm=0; dm<4; dm++) oacc[rt][dm][r] *= a;
            }
        }

        // ---- PV in two K-halves (per-wave 32x32 P buffer reused) ----
        #pragma unroll
        for (int h=0; h<2; h++){
            // pack P cols [h*32, h*32+32)
            #pragma unroll
            for (int rn=0; rn<2; rn++){
                #pragma unroll
                for (int cm2=0; cm2<2; cm2++){
                    const int cm = h*2 + cm2;
                    short hi[4], lo[4];
                    #pragma unroll
                    for (int r=0; r<4; r++){
                        float p = s[cm][rn][r];
                        hi[r] = f2bf(p);
                        lo[r] = f2bf(p - bf2f(hi[r]));
                    }
                    int row = rn*16 + ln;
                    int si = (row*32 + cm2*16 + g*4) ^ ((row&7)<<3);
                    *(bf16x4*)&lPhi[w][si] = (bf16x4){hi[0],hi[1],hi[2],hi[3]};
                    *(bf16x4*)&lPlo[w][si] = (bf16x4){lo[0],lo[1],lo[2],lo[3]};
                }
            }
            // PV with ks2 = h
            bf16x8 ph[2], pl[2], vh[4], vl[4];
            #pragma unroll
            for (int rt=0; rt<2; rt++){
                int row = rt*16 + ln;
                int si = (row*32 + g*8) ^ ((row&7)<<3);
                ph[rt] = *(const bf16x8*)&lPhi[w][si];
                pl[rt] = *(const bf16x8*)&lPlo[w][si];
            }
            #pragma unroll
            for (int dm=0; dm<4; dm++){
                int si = ((dm*16 + ln)*64 + h*32 + g*8) ^ swz;
                vh[dm] = *(const bf16x8*)&lVhi[si];
                vl[dm] = *(const bf16x8*)&lVlo[si];
            }
            #pragma unroll
            for (int rt=0; rt<2; rt++){
                #pragma unroll
                for (int dm=0; dm<4; dm++){
                    oacc[rt][dm] = mfma16(ph[rt], vh[dm], oacc[rt][dm]);
                    oacc[rt][dm] = mfma16(ph[rt], vl[dm], oacc[rt][dm]);
                    oacc[rt][dm] = mfma16(pl[rt], vh[dm], oacc[rt][dm]);
                }
            }
        }
    }

    // ---- epilogue: O /= l, fp32 head-major store ----
    #pragma unroll
    for (int rt=0; rt<2; rt++){
        float inv[4];
        #pragma unroll
        for (int r=0; r<4; r++) inv[r] = 1.0f / __shfl(l_run[rt], g*4 + r);
        #pragma unroll
        for (int dm=0; dm<4; dm++){
            #pragma unroll
            for (int r=0; r<4; r++){
                ob[((size_t)bh*SEQ + qt*128 + w*32 + rt*16 + g*4 + r)*DKH + dm*16 + ln]
                    = oacc[rt][dm][r] * inv[r];
            }
        }
    }
}

// ---------------------------------------------------------------------------
// Kernel C: output projection via bf16-split MFMA. BK=32 + 4-blocks/CU.
// ---------------------------------------------------------------------------
__global__ __launch_bounds__(256, 4)
void gemm_out_kernel(const float* __restrict__ ao,
                     const float* __restrict__ Wo,
                     float* __restrict__ out)
{
    __shared__ short lAh[128*32], lAl[128*32], lBh[128*32], lBl[128*32];

    const int t  = threadIdx.x;
    const int w  = t >> 6, l = t & 63;
    const int ln = l & 15, g = l >> 4;
    const int wr = w >> 1, wc = w & 1;
    const int m0 = blockIdx.x * 128, n0 = blockIdx.y * 128;

    f32x4 acc[4][4];
    #pragma unroll
    for (int mi=0;mi<4;mi++)
        #pragma unroll
        for (int ni=0;ni<4;ni++) acc[mi][ni] = (f32x4){0.f,0.f,0.f,0.f};

    for (int k0 = 0; k0 < D_MODEL; k0 += 32){
        const int hh = k0 >> 6;        // head index (2 K-steps per head)
        const int kin = k0 & 63;       // offset within head
        __syncthreads();
        #pragma unroll
        for (int i=0;i<4;i++){
            int c    = i*256 + t;
            int row  = c >> 3;
            int col4 = (c & 7) << 2;
            int si   = (row*32 + col4) ^ ((row & 7) << 3);
            const int m = m0 + row;
            const int b = m >> 11;
            const int s = m & 2047;
            float4 fa = *(const float4*)&ao[(((size_t)(b*NHEAD + hh))*SEQ + s)*DKH + kin + col4];
            uint2 ah_, al_;
            split4(fa, &ah_, &al_);
            *(uint2*)&lAh[si] = ah_;
            *(uint2*)&lAl[si] = al_;
            float4 fb = *(const float4*)&Wo[(size_t)(n0+row)*D_MODEL + k0 + col4];
            uint2 bh_, bl_;
            split4(fb, &bh_, &bl_);
            *(uint2*)&lBh[si] = bh_;
            *(uint2*)&lBl[si] = bl_;
        }
        __syncthreads();

        bf16x8 ah[4], al[4], bh[4], bl[4];
        #pragma unroll
        for (int mi=0;mi<4;mi++){
            int row = wr*64 + mi*16 + ln;
            int si  = (row*32 + g*8) ^ ((row & 7) << 3);
            ah[mi] = *(const bf16x8*)&lAh[si];
            al[mi] = *(const bf16x8*)&lAl[si];
        }
        #pragma unroll
        for (int ni=0;ni<4;ni++){
            int row = wc*64 + ni*16 + ln;
            int si  = (row*32 + g*8) ^ ((row & 7) << 3);
            bh[ni] = *(const bf16x8*)&lBh[si];
            bl[ni] = *(const bf16x8*)&lBl[si];
        }
        #pragma unroll
        for (int mi=0;mi<4;mi++)
            #pragma unroll
            for (int ni=0;ni<4;ni++){
                acc[mi][ni] = mfma16(ah[mi], bh[ni], acc[mi][ni]);
                acc[mi][ni] = mfma16(ah[mi], bl[ni], acc[mi][ni]);
                acc[mi][ni] = mfma16(al[mi], bh[ni], acc[mi][ni]);
            }
    }

    #pragma unroll
    for (int mi=0;mi<4;mi++){
        #pragma unroll
        for (int ni=0;ni<4;ni++){
            const int n = n0 + wc*64 + ni*16 + ln;
            #pragma unroll
            for (int r=0;r<4;r++){
                const int m = m0 + wr*64 + mi*16 + g*4 + r;
                out[(size_t)m*D_MODEL + n] = acc[mi][ni][r];
            }
        }
    }
}

// ---------------------------------------------------------------------------
extern "C" void kernel_launch(void* const* d_in, const int* in_sizes, int n_in,
                              void* d_out, int out_size, void* d_ws, size_t ws_size,
                              hipStream_t stream)
{
    (void)in_sizes; (void)n_in; (void)out_size; (void)ws_size;
    const float* x   = (const float*)d_in[0];
    const int*   pos = (const int*)  d_in[1];
    const float* Wq  = (const float*)d_in[2];
    const float* Wk  = (const float*)d_in[3];
    const float* Wv  = (const float*)d_in[4];
    const float* Wo  = (const float*)d_in[5];
    float* out = (float*)d_out;

    // Workspace: exactly 96 MB (proven safe).
    const size_t per = (size_t)BH*SEQ*DKH;   // 8M floats = 32 MB
    float* qb = (float*)d_ws;
    float* kb = qb + per;
    float* vb = kb + per;
    float* ao = qb;   // attention output overwrites Q buffer (each flash block
                      // reads its own Q rows into registers before writing)

    dim3 gA(MROWS/128, D_MODEL/128, 3);
    gemm_qkv_kernel<<<gA, 256, 0, stream>>>(x, pos, Wq, Wk, Wv, qb, kb, vb);

    dim3 gB(SEQ/128, BH);
    flash_mfma_kernel<<<gB, 256, 0, stream>>>(qb, kb, vb, ao);

    dim3 gC(MROWS/128, D_MODEL/128);
    gemm_out_kernel<<<gC, 256, 0, stream>>>(ao, Wo, out);
}